// Round 16
// baseline (317.620 us; speedup 1.0000x reference)
//
#include <hip/hip_runtime.h>
#include <hip/hip_bf16.h>
#include <stdint.h>

// SpatialMHA: B=64 S=256 E=1024 H=16 D=64
// qkv = x @ Win^T + bin ; attn with additive spatial bias ; out = x + ctx @ Wout^T + bout

typedef __attribute__((ext_vector_type(8))) __bf16 bf16x8;
typedef __attribute__((ext_vector_type(4))) float f32x4;

#define DEVI static __device__ __forceinline__

DEVI unsigned short f2bf(float f) {           // fp32 -> bf16 round-to-nearest-even
  union { float f; unsigned u; } x; x.f = f;
  unsigned r = x.u + 0x7fffu + ((x.u >> 16) & 1u);
  return (unsigned short)(r >> 16);
}

DEVI float bf2f(unsigned short h) {
  union { unsigned u; float f; } x; x.u = (unsigned)h << 16; return x.f;
}

typedef unsigned int __attribute__((address_space(1))) u32_g;
typedef unsigned int __attribute__((address_space(3))) u32_l;

DEVI void g2l16(const unsigned short* g, unsigned short* l) {
  // async global->LDS, 16B per lane; LDS dest = wave-uniform base + lane*16
  __builtin_amdgcn_global_load_lds((const u32_g*)g, (u32_l*)l, 16, 0, 0);
}

// ---------------------------------------------------------------- fp32->bf16
__global__ __launch_bounds__(256) void cvt_kernel(const float* __restrict__ s,
                                                  unsigned short* __restrict__ d, int n) {
  int i = (blockIdx.x * 256 + threadIdx.x) * 4;
  if (i >= n) return;
  float4 v = *(const float4*)(s + i);
  ushort4 o;
  o.x = f2bf(v.x); o.y = f2bf(v.y); o.z = f2bf(v.z); o.w = f2bf(v.w);
  *(ushort4*)(d + i) = o;
}

// ---------------------------------------------------------------- 128x128 GEMM (R12 winner)
// R0/m97 structure (128^2, 4 waves 2x2, BK=64, 32KB LDS, __syncthreads per
// K-step) + granule XOR swizzle: ~124us, MfmaUtil 37%, 0 conflicts, occ 39%.
// R15: AF32 path fuses the fp32->bf16 conversion of x INTO the A-staging
// (removes the 16us standalone cvt-x + 96MB HBM round-trip): 2x float4 load
// (LINEAR source granule lane&7 -> coalesced 64B runs) -> pack 8 bf16 ->
// 2x ds_write_b64 to DEST granule (lane&7)^row8. Dest-XOR (not source-XOR)
// keeps writes conflict-free: same-granule lanes span rows 0..7 -> XOR spreads
// them over 8 granule positions = 32 banks. Content map As[row][g] =
// A[row][g^(row&7)] is identical to the g2l16 path, so LOADF is unchanged.
// B (weights, already bf16) stays global_load_lds.
template <int EPI, int AF32>
__global__ __launch_bounds__(256, 2)
void gemm_bt(const unsigned short* __restrict__ Abf,
             const float* __restrict__ Af,
             const unsigned short* __restrict__ Bw,
             const float* __restrict__ bias,
             unsigned short* __restrict__ Qo,
             unsigned short* __restrict__ Ko,
             unsigned short* __restrict__ VTo,
             const float* __restrict__ Xres,
             float* __restrict__ Out) {
  __shared__ unsigned short As[8192];   // [128][64] bf16, 16KB, granule-swizzled
  __shared__ unsigned short Bs[8192];
  const int lane = threadIdx.x & 63, wave = threadIdx.x >> 6;
  const int l15 = lane & 15, lg = lane >> 4;
  const int wr = wave >> 1, wc = wave & 1;
  const int am0 = blockIdx.x * 128, bn0 = blockIdx.y * 128;

  const int srow8 = lane >> 3;                    // row within 8-row seg
  const int sgsrc = (lane & 7) ^ srow8;           // swizzled source granule (g2l16 path)

  f32x4 acc[4][4] = {};

  for (int kt = 0; kt < 16; ++kt) {
    const int k0 = kt * 64;
#pragma unroll
    for (int i = 0; i < 4; ++i) {
      const int seg = wave * 4 + i;               // 0..15
      const int row = seg * 8 + srow8;            // 0..127
      if (AF32) {
        const float* p = Af + (size_t)(am0 + row) * 1024 + k0 + (lane & 7) * 8;
        float4 v0 = *(const float4*)p;
        float4 v1 = *(const float4*)(p + 4);
        unsigned long long lo = (unsigned long long)f2bf(v0.x)
          | ((unsigned long long)f2bf(v0.y) << 16)
          | ((unsigned long long)f2bf(v0.z) << 32)
          | ((unsigned long long)f2bf(v0.w) << 48);
        unsigned long long hi = (unsigned long long)f2bf(v1.x)
          | ((unsigned long long)f2bf(v1.y) << 16)
          | ((unsigned long long)f2bf(v1.z) << 32)
          | ((unsigned long long)f2bf(v1.w) << 48);
        unsigned long long* d = (unsigned long long*)&As[row * 64 + (((lane & 7) ^ srow8) << 3)];
        d[0] = lo; d[1] = hi;
      } else {
        g2l16(Abf + (size_t)(am0 + row) * 1024 + k0 + sgsrc * 8, &As[seg * 512]);
      }
      g2l16(Bw + (size_t)(bn0 + row) * 1024 + k0 + sgsrc * 8, &Bs[seg * 512]);
    }
    __syncthreads();   // drains vmcnt(0) for global_load_lds + lgkm for ds_writes
#pragma unroll
    for (int kk = 0; kk < 2; ++kk) {
      bf16x8 a[4], b[4];
#pragma unroll
      for (int mf = 0; mf < 4; ++mf) {
        const int row_ = wr * 64 + mf * 16 + l15;
        a[mf] = *(const bf16x8*)((const char*)As + row_ * 128 + (((kk * 4 + lg) ^ (row_ & 7)) << 4));
      }
#pragma unroll
      for (int nf = 0; nf < 4; ++nf) {
        const int row_ = wc * 64 + nf * 16 + l15;
        b[nf] = *(const bf16x8*)((const char*)Bs + row_ * 128 + (((kk * 4 + lg) ^ (row_ & 7)) << 4));
      }
#pragma unroll
      for (int mf = 0; mf < 4; ++mf)
#pragma unroll
        for (int nf = 0; nf < 4; ++nf)
          acc[mf][nf] = __builtin_amdgcn_mfma_f32_16x16x32_bf16(a[mf], b[nf], acc[mf][nf], 0, 0, 0);
    }
    __syncthreads();
  }

  // C frag mapping: col = bn0 + wc*64 + nf*16 + l15 ; row = am0 + wr*64 + mf*16 + lg*4 + r
  if (EPI == 0) {
#pragma unroll
    for (int nf = 0; nf < 4; ++nf) {
      const int col = bn0 + wc * 64 + nf * 16 + l15;   // 0..3071
      const int which = col >> 10;                     // 0=Q 1=K 2=V (uniform per block)
      const int e = col & 1023;
      const int hh = e >> 6, dd = e & 63;
      const float bv = bias[col];
#pragma unroll
      for (int mf = 0; mf < 4; ++mf) {
        const int row0 = am0 + wr * 64 + mf * 16 + lg * 4;  // multiple of 4
        const int bb = row0 >> 8;
        const int s0 = row0 & 255;
        if (which == 2) {
          unsigned long long pk = 0;
#pragma unroll
          for (int r = 0; r < 4; ++r)
            pk |= (unsigned long long)f2bf(acc[mf][nf][r] + bv) << (16 * r);
          *(unsigned long long*)&VTo[((size_t)(bb * 16 + hh) * 64 + dd) * 256 + s0] = pk;
        } else if (which == 0) {
          // Q pre-scaled by 1/sqrt(D)=0.125 (exact bf16 exponent shift)
#pragma unroll
          for (int r = 0; r < 4; ++r)
            Qo[((size_t)(bb * 16 + hh) * 256 + s0 + r) * 64 + dd] = f2bf((acc[mf][nf][r] + bv) * 0.125f);
        } else {
#pragma unroll
          for (int r = 0; r < 4; ++r)
            Ko[((size_t)(bb * 16 + hh) * 256 + s0 + r) * 64 + dd] = f2bf(acc[mf][nf][r] + bv);
        }
      }
    }
  } else {
#pragma unroll
    for (int nf = 0; nf < 4; ++nf) {
      const int col = bn0 + wc * 64 + nf * 16 + l15;
      const float bv = bias[col];
#pragma unroll
      for (int mf = 0; mf < 4; ++mf) {
#pragma unroll
        for (int r = 0; r < 4; ++r) {
          const int row = am0 + wr * 64 + mf * 16 + lg * 4 + r;
          const size_t idx = (size_t)row * 1024 + col;
          Out[idx] = Xres[idx] + acc[mf][nf][r] + bv;
        }
      }
    }
  }
}

// ---------------------------------------------------------------- fused attention
// R15 vs R14: V register double-buffer (T14). Chunk c issues chunk c+1's V loads
// at its TOP, so the ~900cy cold-HBM latency hides under softmax+PV instead of
// stalling the next chunk (unroll-1 loop had zero cross-chunk overlap). +16 VGPR
// (vbA/vbB static names per rule #20), manual 2-unroll. All else frozen from
// R14: K bulk-stage LDS (granule swizzle, order-independent vmcnt(0) handshake),
// T5 setprio on both MFMA clusters, T13 defer-max, bias bf16, Q pre-scaled.
__global__ __launch_bounds__(256, 2)
void attn_kernel(const unsigned short* __restrict__ Qg,
                 const unsigned short* __restrict__ Kg,
                 const unsigned short* __restrict__ VTg,
                 const unsigned short* __restrict__ biasbf,
                 unsigned short* __restrict__ ctx) {
  __shared__ unsigned short Ks[256 * 64];   // 32KB swizzled K
  __shared__ unsigned short P[4][64][40];   // per-wave [q][k32], pad 32->40 (20KB)
  const int lane = threadIdx.x & 63, wave = threadIdx.x >> 6;
  const int l15 = lane & 15, lg = lane >> 4;
  const int bh = blockIdx.x;
  const int bb = bh >> 4, hh = bh & 15;
  const size_t base = (size_t)bh * (256 * 64);
  const int q0 = wave * 64;

  // ---- bulk K stage: 2048 granules(16B); issue j covers rows (wave*8+j)*8..+7
#pragma unroll
  for (int j = 0; j < 8; ++j) {
    const int r0 = (wave * 8 + j) * 8;
    const int row = r0 + (lane >> 3);
    const int gsrc = (lane & 7) ^ (row & 7);
    g2l16(&Kg[base + (size_t)row * 64 + gsrc * 8], &Ks[r0 * 64]);
  }
  // Order-independent drain: ALL this wave's vmem done before signaling.
  asm volatile("s_waitcnt vmcnt(0)" ::: "memory");
  __builtin_amdgcn_sched_barrier(0);
  __builtin_amdgcn_s_barrier();                     // all waves' K staged

  // Q fragments (after barrier; pre-scaled by 0.125 in gemm0)
  bf16x8 qfr[4][2];
#pragma unroll
  for (int qi = 0; qi < 4; ++qi)
#pragma unroll
    for (int kc = 0; kc < 2; ++kc)
      qfr[qi][kc] = *(const bf16x8*)&Qg[base + (size_t)(q0 + qi * 16 + l15) * 64 + kc * 32 + lg * 8];

  f32x4 o[4][4] = {};
  float mrow[4], lrow[4];
#pragma unroll
  for (int i = 0; i < 4; ++i) { mrow[i] = -1e30f; lrow[i] = 0.f; }

  bf16x8 vbA[4], vbB[4];
#pragma unroll
  for (int df = 0; df < 4; ++df)    // V for chunk 0
    vbA[df] = *(const bf16x8*)&VTg[base + (size_t)(df * 16 + l15) * 256 + lg * 8];

  // One chunk: uses VC for PV; if PRE, prefetches chunk c+1's V into VN.
#define CHUNKA(c, VC, VN, PRE) { \
    const int ck = (c) * 32; \
    if (PRE) { \
      _Pragma("unroll") \
      for (int df = 0; df < 4; ++df) \
        VN[df] = *(const bf16x8*)&VTg[base + (size_t)(df * 16 + l15) * 256 + ck + 32 + lg * 8]; \
    } \
    ushort4 bbf[2][4]; \
    _Pragma("unroll") \
    for (int kr = 0; kr < 2; ++kr) \
      _Pragma("unroll") \
      for (int qi = 0; qi < 4; ++qi) \
        bbf[kr][qi] = *(const ushort4*)&biasbf[(q0 + qi * 16 + l15) * 256 + ck + kr * 16 + lg * 4]; \
    bf16x8 kf[2][2]; \
    _Pragma("unroll") \
    for (int kr = 0; kr < 2; ++kr) \
      _Pragma("unroll") \
      for (int kc = 0; kc < 2; ++kc) { \
        const int row = ck + kr * 16 + l15; \
        const int g = (kc * 4 + lg) ^ (row & 7); \
        kf[kr][kc] = *(const bf16x8*)&Ks[row * 64 + g * 8]; \
      } \
    f32x4 s[2][4] = {}; \
    __builtin_amdgcn_s_setprio(1); \
    _Pragma("unroll") \
    for (int kr = 0; kr < 2; ++kr) \
      _Pragma("unroll") \
      for (int qi = 0; qi < 4; ++qi) \
        _Pragma("unroll") \
        for (int kc = 0; kc < 2; ++kc) \
          s[kr][qi] = __builtin_amdgcn_mfma_f32_16x16x32_bf16(kf[kr][kc], qfr[qi][kc], s[kr][qi], 0, 0, 0); \
    __builtin_amdgcn_s_setprio(0); \
    float cmax[4]; \
    _Pragma("unroll") \
    for (int qi = 0; qi < 4; ++qi) cmax[qi] = -1e30f; \
    _Pragma("unroll") \
    for (int kr = 0; kr < 2; ++kr) \
      _Pragma("unroll") \
      for (int qi = 0; qi < 4; ++qi) { \
        const unsigned short* bp = (const unsigned short*)&bbf[kr][qi]; \
        _Pragma("unroll") \
        for (int r = 0; r < 4; ++r) { \
          float v = s[kr][qi][r] + bf2f(bp[r]); \
          s[kr][qi][r] = v; \
          cmax[qi] = fmaxf(cmax[qi], v); \
        } \
      } \
    _Pragma("unroll") \
    for (int qi = 0; qi < 4; ++qi) { \
      cmax[qi] = fmaxf(cmax[qi], __shfl_xor(cmax[qi], 16, 64)); \
      cmax[qi] = fmaxf(cmax[qi], __shfl_xor(cmax[qi], 32, 64)); \
    } \
    int defer = 1; \
    _Pragma("unroll") \
    for (int qi = 0; qi < 4; ++qi) defer &= (cmax[qi] - mrow[qi] <= 8.f); \
    const int full = !__all(defer); \
    float resc[4]; \
    _Pragma("unroll") \
    for (int qi = 0; qi < 4; ++qi) { \
      if (full) { \
        float mn = fmaxf(mrow[qi], cmax[qi]); \
        resc[qi] = __expf(mrow[qi] - mn); \
        mrow[qi] = mn; \
      } else resc[qi] = 1.f; \
    } \
    float csum[4]; \
    _Pragma("unroll") \
    for (int qi = 0; qi < 4; ++qi) csum[qi] = 0.f; \
    _Pragma("unroll") \
    for (int kr = 0; kr < 2; ++kr) \
      _Pragma("unroll") \
      for (int qi = 0; qi < 4; ++qi) \
        _Pragma("unroll") \
        for (int r = 0; r < 4; ++r) { \
          float e = __expf(s[kr][qi][r] - mrow[qi]); \
          s[kr][qi][r] = e; \
          csum[qi] += e; \
        } \
    _Pragma("unroll") \
    for (int qi = 0; qi < 4; ++qi) { \
      csum[qi] += __shfl_xor(csum[qi], 16, 64); \
      csum[qi] += __shfl_xor(csum[qi], 32, 64); \
      lrow[qi] = lrow[qi] * resc[qi] + csum[qi]; \
    } \
    _Pragma("unroll") \
    for (int kr = 0; kr < 2; ++kr) \
      _Pragma("unroll") \
      for (int qi = 0; qi < 4; ++qi) { \
        unsigned long long pk = 0; \
        _Pragma("unroll") \
        for (int r = 0; r < 4; ++r) \
          pk |= (unsigned long long)f2bf(s[kr][qi][r]) << (16 * r); \
        *(unsigned long long*)&P[wave][qi * 16 + l15][kr * 16 + lg * 4] = pk; \
      } \
    asm volatile("s_waitcnt lgkmcnt(0)" ::: "memory"); \
    if (full) { \
      _Pragma("unroll") \
      for (int qrf = 0; qrf < 4; ++qrf) \
        _Pragma("unroll") \
        for (int r = 0; r < 4; ++r) { \
          float f = __shfl(resc[qrf], lg * 4 + r, 64); \
          _Pragma("unroll") \
          for (int df = 0; df < 4; ++df) o[qrf][df][r] *= f; \
        } \
    } \
    bf16x8 pa[4]; \
    _Pragma("unroll") \
    for (int qrf = 0; qrf < 4; ++qrf) \
      pa[qrf] = *(const bf16x8*)&P[wave][qrf * 16 + l15][lg * 8]; \
    __builtin_amdgcn_s_setprio(1); \
    _Pragma("unroll") \
    for (int qrf = 0; qrf < 4; ++qrf) \
      _Pragma("unroll") \
      for (int df = 0; df < 4; ++df) \
        o[qrf][df] = __builtin_amdgcn_mfma_f32_16x16x32_bf16(pa[qrf], VC[df], o[qrf][df], 0, 0, 0); \
    __builtin_amdgcn_s_setprio(0); \
  }

#pragma unroll 1
  for (int c2 = 0; c2 < 4; ++c2) {
    CHUNKA(2 * c2,     vbA, vbB, 1)
    CHUNKA(2 * c2 + 1, vbB, vbA, (c2 < 3))
  }
#undef CHUNKA

  // normalize and write ctx [B,S,E] bf16
#pragma unroll
  for (int qrf = 0; qrf < 4; ++qrf)
#pragma unroll
    for (int r = 0; r < 4; ++r) {
      float li = __shfl(lrow[qrf], lg * 4 + r, 64);
      float inv = 1.0f / li;
      const int q = q0 + qrf * 16 + lg * 4 + r;
#pragma unroll
      for (int df = 0; df < 4; ++df) {
        const int d = df * 16 + l15;
        ctx[((size_t)(bb * 256 + q) * 16 + hh) * 64 + d] = f2bf(o[qrf][df][r] * inv);
      }
    }
}

// ---------------------------------------------------------------- launch
extern "C" void kernel_launch(void* const* d_in, const int* in_sizes, int n_in,
                              void* d_out, int out_size, void* d_ws, size_t ws_size,
                              hipStream_t stream) {
  const float* x  = (const float*)d_in[0];
  const float* wi = (const float*)d_in[1];
  const float* bi = (const float*)d_in[2];
  const float* wo = (const float*)d_in[3];
  const float* bo = (const float*)d_in[4];
  const float* sb = (const float*)d_in[5];
  float* out = (float*)d_out;

  char* ws = (char*)d_ws;
  // ws layout (bytes): ctx 33554432 | w_in 6291456 | w_out 2097152 | Q | K | VT
  unsigned short* ctx  = (unsigned short*)(ws);
  unsigned short* winb = (unsigned short*)(ws + 33554432u);
  unsigned short* wob  = (unsigned short*)(ws + 39845888u);
  unsigned short* Qb   = (unsigned short*)(ws + 41943040u);
  unsigned short* Kb   = (unsigned short*)(ws + 75497472u);
  unsigned short* VTb  = (unsigned short*)(ws + 109051904u);
  unsigned short* sbbf = winb;  // w_in dead after gemm0; bias-bf16 cvt'd there

  cvt_kernel<<<3072, 256, 0, stream>>>(wi, winb, 3145728);
  cvt_kernel<<<1024, 256, 0, stream>>>(wo, wob, 1048576);

  // QKV: M=16384 N=3072 K=1024; A = x fp32, converted in-kernel (AF32=1)
  gemm_bt<0, 1><<<dim3(128, 24), 256, 0, stream>>>(nullptr, x, winb, bi, Qb, Kb, VTb, nullptr, nullptr);

  // bias -> bf16 into the now-dead w_in region (64 blocks, 65536 elems)
  cvt_kernel<<<64, 256, 0, stream>>>(sb, sbbf, 65536);

  // attention: one block per (b,h)
  attn_kernel<<<1024, 256, 0, stream>>>(Qb, Kb, VTb, sbbf, ctx);

  // out-proj + residual: M=16384 N=1024 K=1024; A = ctx bf16 (AF32=0)
  gemm_bt<1, 0><<<dim3(128, 8), 256, 0, stream>>>(ctx, nullptr, wob, bo, nullptr, nullptr, nullptr, x, out);
}

// Round 17
// 276.693 us; speedup vs baseline: 1.1479x; 1.1479x over previous
//
#include <hip/hip_runtime.h>
#include <hip/hip_bf16.h>
#include <stdint.h>

// SpatialMHA: B=64 S=256 E=1024 H=16 D=64
// qkv = x @ Win^T + bin ; attn with additive spatial bias ; out = x + ctx @ Wout^T + bout

typedef __attribute__((ext_vector_type(8))) __bf16 bf16x8;
typedef __attribute__((ext_vector_type(4))) float f32x4;

#define DEVI static __device__ __forceinline__

DEVI unsigned short f2bf(float f) {           // fp32 -> bf16 round-to-nearest-even
  union { float f; unsigned u; } x; x.f = f;
  unsigned r = x.u + 0x7fffu + ((x.u >> 16) & 1u);
  return (unsigned short)(r >> 16);
}

DEVI float bf2f(unsigned short h) {
  union { unsigned u; float f; } x; x.u = (unsigned)h << 16; return x.f;
}

typedef unsigned int __attribute__((address_space(1))) u32_g;
typedef unsigned int __attribute__((address_space(3))) u32_l;

DEVI void g2l16(const unsigned short* g, unsigned short* l) {
  // async global->LDS, 16B per lane; LDS dest = wave-uniform base + lane*16
  __builtin_amdgcn_global_load_lds((const u32_g*)g, (u32_l*)l, 16, 0, 0);
}

// ---------------------------------------------------------------- fp32->bf16
__global__ __launch_bounds__(256) void cvt_kernel(const float* __restrict__ s,
                                                  unsigned short* __restrict__ d, int n) {
  int i = (blockIdx.x * 256 + threadIdx.x) * 4;
  if (i >= n) return;
  float4 v = *(const float4*)(s + i);
  ushort4 o;
  o.x = f2bf(v.x); o.y = f2bf(v.y); o.z = f2bf(v.z); o.w = f2bf(v.w);
  *(ushort4*)(d + i) = o;
}

// ---------------------------------------------------------------- 128x128 GEMM (R12/R14 winner, FROZEN)
// R0/m97 structure (128^2, 4 waves 2x2, BK=64, 32KB LDS, global_load_lds w16,
// __syncthreads per K-step) + granule XOR swizzle: ~124us, MfmaUtil 37%,
// 0 bank conflicts, occupancy 39%. R15's fused-fp32-A variant REGRESSED
// (185us: fp32 A doubles re-read bytes past L3, f2bf packing serializes on the
// VALU the MFMA loop needs — FETCH 161->355MB, MfmaUtil 24.5) -> reverted.
template <int EPI>
__global__ __launch_bounds__(256, 2)
void gemm_bt(const unsigned short* __restrict__ A,
             const unsigned short* __restrict__ Bw,
             const float* __restrict__ bias,
             unsigned short* __restrict__ Qo,
             unsigned short* __restrict__ Ko,
             unsigned short* __restrict__ VTo,
             const float* __restrict__ Xres,
             float* __restrict__ Out) {
  __shared__ unsigned short As[8192];   // [128][64] bf16, 16KB, granule-swizzled
  __shared__ unsigned short Bs[8192];
  const int lane = threadIdx.x & 63, wave = threadIdx.x >> 6;
  const int l15 = lane & 15, lg = lane >> 4;
  const int wr = wave >> 1, wc = wave & 1;
  const int am0 = blockIdx.x * 128, bn0 = blockIdx.y * 128;

  const int srow8 = lane >> 3;                    // row within 8-row seg
  const int sgsrc = (lane & 7) ^ srow8;           // swizzled source granule

  f32x4 acc[4][4] = {};

  for (int kt = 0; kt < 16; ++kt) {
    const int k0 = kt * 64;
#pragma unroll
    for (int i = 0; i < 4; ++i) {
      const int seg = wave * 4 + i;               // 0..15
      const int row = seg * 8 + srow8;            // 0..127
      g2l16(A  + (size_t)(am0 + row) * 1024 + k0 + sgsrc * 8, &As[seg * 512]);
      g2l16(Bw + (size_t)(bn0 + row) * 1024 + k0 + sgsrc * 8, &Bs[seg * 512]);
    }
    __syncthreads();   // drains vmcnt(0) for global_load_lds
#pragma unroll
    for (int kk = 0; kk < 2; ++kk) {
      bf16x8 a[4], b[4];
#pragma unroll
      for (int mf = 0; mf < 4; ++mf) {
        const int row_ = wr * 64 + mf * 16 + l15;
        a[mf] = *(const bf16x8*)((const char*)As + row_ * 128 + (((kk * 4 + lg) ^ (row_ & 7)) << 4));
      }
#pragma unroll
      for (int nf = 0; nf < 4; ++nf) {
        const int row_ = wc * 64 + nf * 16 + l15;
        b[nf] = *(const bf16x8*)((const char*)Bs + row_ * 128 + (((kk * 4 + lg) ^ (row_ & 7)) << 4));
      }
#pragma unroll
      for (int mf = 0; mf < 4; ++mf)
#pragma unroll
        for (int nf = 0; nf < 4; ++nf)
          acc[mf][nf] = __builtin_amdgcn_mfma_f32_16x16x32_bf16(a[mf], b[nf], acc[mf][nf], 0, 0, 0);
    }
    __syncthreads();
  }

  // C frag mapping: col = bn0 + wc*64 + nf*16 + l15 ; row = am0 + wr*64 + mf*16 + lg*4 + r
  if (EPI == 0) {
#pragma unroll
    for (int nf = 0; nf < 4; ++nf) {
      const int col = bn0 + wc * 64 + nf * 16 + l15;   // 0..3071
      const int which = col >> 10;                     // 0=Q 1=K 2=V (uniform per block)
      const int e = col & 1023;
      const int hh = e >> 6, dd = e & 63;
      const float bv = bias[col];
#pragma unroll
      for (int mf = 0; mf < 4; ++mf) {
        const int row0 = am0 + wr * 64 + mf * 16 + lg * 4;  // multiple of 4
        const int bb = row0 >> 8;
        const int s0 = row0 & 255;
        if (which == 2) {
          unsigned long long pk = 0;
#pragma unroll
          for (int r = 0; r < 4; ++r)
            pk |= (unsigned long long)f2bf(acc[mf][nf][r] + bv) << (16 * r);
          *(unsigned long long*)&VTo[((size_t)(bb * 16 + hh) * 64 + dd) * 256 + s0] = pk;
        } else if (which == 0) {
          // Q pre-scaled by 1/sqrt(D)=0.125 (exact bf16 exponent shift)
#pragma unroll
          for (int r = 0; r < 4; ++r)
            Qo[((size_t)(bb * 16 + hh) * 256 + s0 + r) * 64 + dd] = f2bf((acc[mf][nf][r] + bv) * 0.125f);
        } else {
#pragma unroll
          for (int r = 0; r < 4; ++r)
            Ko[((size_t)(bb * 16 + hh) * 256 + s0 + r) * 64 + dd] = f2bf(acc[mf][nf][r] + bv);
        }
      }
    }
  } else {
#pragma unroll
    for (int nf = 0; nf < 4; ++nf) {
      const int col = bn0 + wc * 64 + nf * 16 + l15;
      const float bv = bias[col];
#pragma unroll
      for (int mf = 0; mf < 4; ++mf) {
#pragma unroll
        for (int r = 0; r < 4; ++r) {
          const int row = am0 + wr * 64 + mf * 16 + lg * 4 + r;
          const size_t idx = (size_t)row * 1024 + col;
          Out[idx] = Xres[idx] + acc[mf][nf][r] + bv;
        }
      }
    }
  }
}

// ---------------------------------------------------------------- fused attention
// R16: gemm reverted to R14; attn keeps R15's V register double-buffer as the
// SINGLE variable vs the 264us R14 baseline. T14 mechanism: chunk c+1's V loads
// issue at chunk c's top -> ~900cy HBM latency hides under softmax+PV (the
// unroll-1 loop otherwise has zero cross-chunk overlap). +16 VGPR (static
// vbA/vbB names per rule #20), manual 2-unroll. All else frozen from R14:
// K bulk-stage LDS (granule swizzle, order-independent vmcnt(0) handshake),
// T5 setprio on both MFMA clusters, T13 defer-max, bias bf16, Q pre-scaled.
__global__ __launch_bounds__(256, 2)
void attn_kernel(const unsigned short* __restrict__ Qg,
                 const unsigned short* __restrict__ Kg,
                 const unsigned short* __restrict__ VTg,
                 const unsigned short* __restrict__ biasbf,
                 unsigned short* __restrict__ ctx) {
  __shared__ unsigned short Ks[256 * 64];   // 32KB swizzled K
  __shared__ unsigned short P[4][64][40];   // per-wave [q][k32], pad 32->40 (20KB)
  const int lane = threadIdx.x & 63, wave = threadIdx.x >> 6;
  const int l15 = lane & 15, lg = lane >> 4;
  const int bh = blockIdx.x;
  const int bb = bh >> 4, hh = bh & 15;
  const size_t base = (size_t)bh * (256 * 64);
  const int q0 = wave * 64;

  // ---- bulk K stage: 2048 granules(16B); issue j covers rows (wave*8+j)*8..+7
#pragma unroll
  for (int j = 0; j < 8; ++j) {
    const int r0 = (wave * 8 + j) * 8;
    const int row = r0 + (lane >> 3);
    const int gsrc = (lane & 7) ^ (row & 7);
    g2l16(&Kg[base + (size_t)row * 64 + gsrc * 8], &Ks[r0 * 64]);
  }
  // Order-independent drain: ALL this wave's vmem done before signaling.
  asm volatile("s_waitcnt vmcnt(0)" ::: "memory");
  __builtin_amdgcn_sched_barrier(0);
  __builtin_amdgcn_s_barrier();                     // all waves' K staged

  // Q fragments (after barrier; pre-scaled by 0.125 in gemm0)
  bf16x8 qfr[4][2];
#pragma unroll
  for (int qi = 0; qi < 4; ++qi)
#pragma unroll
    for (int kc = 0; kc < 2; ++kc)
      qfr[qi][kc] = *(const bf16x8*)&Qg[base + (size_t)(q0 + qi * 16 + l15) * 64 + kc * 32 + lg * 8];

  f32x4 o[4][4] = {};
  float mrow[4], lrow[4];
#pragma unroll
  for (int i = 0; i < 4; ++i) { mrow[i] = -1e30f; lrow[i] = 0.f; }

  bf16x8 vbA[4], vbB[4];
#pragma unroll
  for (int df = 0; df < 4; ++df)    // V for chunk 0
    vbA[df] = *(const bf16x8*)&VTg[base + (size_t)(df * 16 + l15) * 256 + lg * 8];

  // One chunk: uses VC for PV; if PRE, prefetches chunk c+1's V into VN.
#define CHUNKA(c, VC, VN, PRE) { \
    const int ck = (c) * 32; \
    if (PRE) { \
      _Pragma("unroll") \
      for (int df = 0; df < 4; ++df) \
        VN[df] = *(const bf16x8*)&VTg[base + (size_t)(df * 16 + l15) * 256 + ck + 32 + lg * 8]; \
    } \
    ushort4 bbf[2][4]; \
    _Pragma("unroll") \
    for (int kr = 0; kr < 2; ++kr) \
      _Pragma("unroll") \
      for (int qi = 0; qi < 4; ++qi) \
        bbf[kr][qi] = *(const ushort4*)&biasbf[(q0 + qi * 16 + l15) * 256 + ck + kr * 16 + lg * 4]; \
    bf16x8 kf[2][2]; \
    _Pragma("unroll") \
    for (int kr = 0; kr < 2; ++kr) \
      _Pragma("unroll") \
      for (int kc = 0; kc < 2; ++kc) { \
        const int row = ck + kr * 16 + l15; \
        const int g = (kc * 4 + lg) ^ (row & 7); \
        kf[kr][kc] = *(const bf16x8*)&Ks[row * 64 + g * 8]; \
      } \
    f32x4 s[2][4] = {}; \
    __builtin_amdgcn_s_setprio(1); \
    _Pragma("unroll") \
    for (int kr = 0; kr < 2; ++kr) \
      _Pragma("unroll") \
      for (int qi = 0; qi < 4; ++qi) \
        _Pragma("unroll") \
        for (int kc = 0; kc < 2; ++kc) \
          s[kr][qi] = __builtin_amdgcn_mfma_f32_16x16x32_bf16(kf[kr][kc], qfr[qi][kc], s[kr][qi], 0, 0, 0); \
    __builtin_amdgcn_s_setprio(0); \
    float cmax[4]; \
    _Pragma("unroll") \
    for (int qi = 0; qi < 4; ++qi) cmax[qi] = -1e30f; \
    _Pragma("unroll") \
    for (int kr = 0; kr < 2; ++kr) \
      _Pragma("unroll") \
      for (int qi = 0; qi < 4; ++qi) { \
        const unsigned short* bp = (const unsigned short*)&bbf[kr][qi]; \
        _Pragma("unroll") \
        for (int r = 0; r < 4; ++r) { \
          float v = s[kr][qi][r] + bf2f(bp[r]); \
          s[kr][qi][r] = v; \
          cmax[qi] = fmaxf(cmax[qi], v); \
        } \
      } \
    _Pragma("unroll") \
    for (int qi = 0; qi < 4; ++qi) { \
      cmax[qi] = fmaxf(cmax[qi], __shfl_xor(cmax[qi], 16, 64)); \
      cmax[qi] = fmaxf(cmax[qi], __shfl_xor(cmax[qi], 32, 64)); \
    } \
    int defer = 1; \
    _Pragma("unroll") \
    for (int qi = 0; qi < 4; ++qi) defer &= (cmax[qi] - mrow[qi] <= 8.f); \
    const int full = !__all(defer); \
    float resc[4]; \
    _Pragma("unroll") \
    for (int qi = 0; qi < 4; ++qi) { \
      if (full) { \
        float mn = fmaxf(mrow[qi], cmax[qi]); \
        resc[qi] = __expf(mrow[qi] - mn); \
        mrow[qi] = mn; \
      } else resc[qi] = 1.f; \
    } \
    float csum[4]; \
    _Pragma("unroll") \
    for (int qi = 0; qi < 4; ++qi) csum[qi] = 0.f; \
    _Pragma("unroll") \
    for (int kr = 0; kr < 2; ++kr) \
      _Pragma("unroll") \
      for (int qi = 0; qi < 4; ++qi) \
        _Pragma("unroll") \
        for (int r = 0; r < 4; ++r) { \
          float e = __expf(s[kr][qi][r] - mrow[qi]); \
          s[kr][qi][r] = e; \
          csum[qi] += e; \
        } \
    _Pragma("unroll") \
    for (int qi = 0; qi < 4; ++qi) { \
      csum[qi] += __shfl_xor(csum[qi], 16, 64); \
      csum[qi] += __shfl_xor(csum[qi], 32, 64); \
      lrow[qi] = lrow[qi] * resc[qi] + csum[qi]; \
    } \
    _Pragma("unroll") \
    for (int kr = 0; kr < 2; ++kr) \
      _Pragma("unroll") \
      for (int qi = 0; qi < 4; ++qi) { \
        unsigned long long pk = 0; \
        _Pragma("unroll") \
        for (int r = 0; r < 4; ++r) \
          pk |= (unsigned long long)f2bf(s[kr][qi][r]) << (16 * r); \
        *(unsigned long long*)&P[wave][qi * 16 + l15][kr * 16 + lg * 4] = pk; \
      } \
    asm volatile("s_waitcnt lgkmcnt(0)" ::: "memory"); \
    if (full) { \
      _Pragma("unroll") \
      for (int qrf = 0; qrf < 4; ++qrf) \
        _Pragma("unroll") \
        for (int r = 0; r < 4; ++r) { \
          float f = __shfl(resc[qrf], lg * 4 + r, 64); \
          _Pragma("unroll") \
          for (int df = 0; df < 4; ++df) o[qrf][df][r] *= f; \
        } \
    } \
    bf16x8 pa[4]; \
    _Pragma("unroll") \
    for (int qrf = 0; qrf < 4; ++qrf) \
      pa[qrf] = *(const bf16x8*)&P[wave][qrf * 16 + l15][lg * 8]; \
    __builtin_amdgcn_s_setprio(1); \
    _Pragma("unroll") \
    for (int qrf = 0; qrf < 4; ++qrf) \
      _Pragma("unroll") \
      for (int df = 0; df < 4; ++df) \
        o[qrf][df] = __builtin_amdgcn_mfma_f32_16x16x32_bf16(pa[qrf], VC[df], o[qrf][df], 0, 0, 0); \
    __builtin_amdgcn_s_setprio(0); \
  }

#pragma unroll 1
  for (int c2 = 0; c2 < 4; ++c2) {
    CHUNKA(2 * c2,     vbA, vbB, 1)
    CHUNKA(2 * c2 + 1, vbB, vbA, (c2 < 3))
  }
#undef CHUNKA

  // normalize and write ctx [B,S,E] bf16
#pragma unroll
  for (int qrf = 0; qrf < 4; ++qrf)
#pragma unroll
    for (int r = 0; r < 4; ++r) {
      float li = __shfl(lrow[qrf], lg * 4 + r, 64);
      float inv = 1.0f / li;
      const int q = q0 + qrf * 16 + lg * 4 + r;
#pragma unroll
      for (int df = 0; df < 4; ++df) {
        const int d = df * 16 + l15;
        ctx[((size_t)(bb * 256 + q) * 16 + hh) * 64 + d] = f2bf(o[qrf][df][r] * inv);
      }
    }
}

// ---------------------------------------------------------------- launch
extern "C" void kernel_launch(void* const* d_in, const int* in_sizes, int n_in,
                              void* d_out, int out_size, void* d_ws, size_t ws_size,
                              hipStream_t stream) {
  const float* x  = (const float*)d_in[0];
  const float* wi = (const float*)d_in[1];
  const float* bi = (const float*)d_in[2];
  const float* wo = (const float*)d_in[3];
  const float* bo = (const float*)d_in[4];
  const float* sb = (const float*)d_in[5];
  float* out = (float*)d_out;

  char* ws = (char*)d_ws;
  // ws layout (bytes): x_bf/ctx 33554432 | w_in 6291456 | w_out 2097152 | Q | K | VT
  unsigned short* xbf  = (unsigned short*)(ws);
  unsigned short* winb = (unsigned short*)(ws + 33554432u);
  unsigned short* wob  = (unsigned short*)(ws + 39845888u);
  unsigned short* Qb   = (unsigned short*)(ws + 41943040u);
  unsigned short* Kb   = (unsigned short*)(ws + 75497472u);
  unsigned short* VTb  = (unsigned short*)(ws + 109051904u);
  unsigned short* ctx  = xbf;   // x_bf dead after QKV GEMM; reuse for ctx
  unsigned short* sbbf = winb;  // w_in dead after gemm0; bias-bf16 cvt'd there

  cvt_kernel<<<16384, 256, 0, stream>>>(x, xbf, 16777216);
  cvt_kernel<<<3072, 256, 0, stream>>>(wi, winb, 3145728);
  cvt_kernel<<<1024, 256, 0, stream>>>(wo, wob, 1048576);

  // QKV: M=16384 N=3072 K=1024  (Q pre-scaled by 0.125 in epilogue)
  gemm_bt<0><<<dim3(128, 24), 256, 0, stream>>>(xbf, winb, bi, Qb, Kb, VTb, nullptr, nullptr);

  // bias -> bf16 into the now-dead w_in region (64 blocks, 65536 elems)
  cvt_kernel<<<64, 256, 0, stream>>>(sb, sbbf, 65536);

  // attention: one block per (b,h)
  attn_kernel<<<1024, 256, 0, stream>>>(Qb, Kb, VTb, sbbf, ctx);

  // out-proj + residual: M=16384 N=1024 K=1024
  gemm_bt<1><<<dim3(128, 8), 256, 0, stream>>>(ctx, wob, bo, nullptr, nullptr, nullptr, x, out);
}

// Round 18
// 263.348 us; speedup vs baseline: 1.2061x; 1.0507x over previous
//
#include <hip/hip_runtime.h>
#include <hip/hip_bf16.h>
#include <stdint.h>

// SpatialMHA: B=64 S=256 E=1024 H=16 D=64
// qkv = x @ Win^T + bin ; attn with additive spatial bias ; out = x + ctx @ Wout^T + bout
//
// FINAL CONFIG (R14 = session best, 264.1us):
//  cvt x/w (HBM-bound) -> gemm0 128^2 m97-structure + granule swizzle (124us,
//  MfmaUtil 37%, 0 conflicts, occ 39%) -> attn 1 block/(b,h), K-in-LDS, T5
//  setprio, T13 defer-max (~70us) -> gemm1 (+residual). Documented dead ends:
//  8-wave deep pipelines (R1-R5,R11: TLP loss beats schedule gains), attn occ
//  forcing (R8/R13), XCD swizzle (R10), fused fp32-A staging (R15), V reg
//  double-buffer (R16).

typedef __attribute__((ext_vector_type(8))) __bf16 bf16x8;
typedef __attribute__((ext_vector_type(4))) float f32x4;

#define DEVI static __device__ __forceinline__

DEVI unsigned short f2bf(float f) {           // fp32 -> bf16 round-to-nearest-even
  union { float f; unsigned u; } x; x.f = f;
  unsigned r = x.u + 0x7fffu + ((x.u >> 16) & 1u);
  return (unsigned short)(r >> 16);
}

DEVI float bf2f(unsigned short h) {
  union { unsigned u; float f; } x; x.u = (unsigned)h << 16; return x.f;
}

typedef unsigned int __attribute__((address_space(1))) u32_g;
typedef unsigned int __attribute__((address_space(3))) u32_l;

DEVI void g2l16(const unsigned short* g, unsigned short* l) {
  // async global->LDS, 16B per lane; LDS dest = wave-uniform base + lane*16
  __builtin_amdgcn_global_load_lds((const u32_g*)g, (u32_l*)l, 16, 0, 0);
}

// ---------------------------------------------------------------- fp32->bf16
__global__ __launch_bounds__(256) void cvt_kernel(const float* __restrict__ s,
                                                  unsigned short* __restrict__ d, int n) {
  int i = (blockIdx.x * 256 + threadIdx.x) * 4;
  if (i >= n) return;
  float4 v = *(const float4*)(s + i);
  ushort4 o;
  o.x = f2bf(v.x); o.y = f2bf(v.y); o.z = f2bf(v.z); o.w = f2bf(v.w);
  *(ushort4*)(d + i) = o;
}

// ---------------------------------------------------------------- 128x128 GEMM (R12 winner, FROZEN)
// R0/m97 structure (128^2, 4 waves 2x2, BK=64, 32KB LDS, global_load_lds w16,
// __syncthreads per K-step) + granule XOR swizzle. ~124us, MfmaUtil 37%,
// 0 bank conflicts, occupancy 39% (~3 blocks/CU) — the m97-structure ceiling.
template <int EPI>
__global__ __launch_bounds__(256, 2)
void gemm_bt(const unsigned short* __restrict__ A,
             const unsigned short* __restrict__ Bw,
             const float* __restrict__ bias,
             unsigned short* __restrict__ Qo,
             unsigned short* __restrict__ Ko,
             unsigned short* __restrict__ VTo,
             const float* __restrict__ Xres,
             float* __restrict__ Out) {
  __shared__ unsigned short As[8192];   // [128][64] bf16, 16KB, granule-swizzled
  __shared__ unsigned short Bs[8192];
  const int lane = threadIdx.x & 63, wave = threadIdx.x >> 6;
  const int l15 = lane & 15, lg = lane >> 4;
  const int wr = wave >> 1, wc = wave & 1;
  const int am0 = blockIdx.x * 128, bn0 = blockIdx.y * 128;

  const int srow8 = lane >> 3;                    // row within 8-row seg
  const int sgsrc = (lane & 7) ^ srow8;           // swizzled source granule

  f32x4 acc[4][4] = {};

  for (int kt = 0; kt < 16; ++kt) {
    const int k0 = kt * 64;
#pragma unroll
    for (int i = 0; i < 4; ++i) {
      const int seg = wave * 4 + i;               // 0..15
      const int row = seg * 8 + srow8;            // 0..127
      g2l16(A  + (size_t)(am0 + row) * 1024 + k0 + sgsrc * 8, &As[seg * 512]);
      g2l16(Bw + (size_t)(bn0 + row) * 1024 + k0 + sgsrc * 8, &Bs[seg * 512]);
    }
    __syncthreads();   // drains vmcnt(0) for global_load_lds
#pragma unroll
    for (int kk = 0; kk < 2; ++kk) {
      bf16x8 a[4], b[4];
#pragma unroll
      for (int mf = 0; mf < 4; ++mf) {
        const int row_ = wr * 64 + mf * 16 + l15;
        a[mf] = *(const bf16x8*)((const char*)As + row_ * 128 + (((kk * 4 + lg) ^ (row_ & 7)) << 4));
      }
#pragma unroll
      for (int nf = 0; nf < 4; ++nf) {
        const int row_ = wc * 64 + nf * 16 + l15;
        b[nf] = *(const bf16x8*)((const char*)Bs + row_ * 128 + (((kk * 4 + lg) ^ (row_ & 7)) << 4));
      }
#pragma unroll
      for (int mf = 0; mf < 4; ++mf)
#pragma unroll
        for (int nf = 0; nf < 4; ++nf)
          acc[mf][nf] = __builtin_amdgcn_mfma_f32_16x16x32_bf16(a[mf], b[nf], acc[mf][nf], 0, 0, 0);
    }
    __syncthreads();
  }

  // C frag mapping: col = bn0 + wc*64 + nf*16 + l15 ; row = am0 + wr*64 + mf*16 + lg*4 + r
  if (EPI == 0) {
#pragma unroll
    for (int nf = 0; nf < 4; ++nf) {
      const int col = bn0 + wc * 64 + nf * 16 + l15;   // 0..3071
      const int which = col >> 10;                     // 0=Q 1=K 2=V (uniform per block)
      const int e = col & 1023;
      const int hh = e >> 6, dd = e & 63;
      const float bv = bias[col];
#pragma unroll
      for (int mf = 0; mf < 4; ++mf) {
        const int row0 = am0 + wr * 64 + mf * 16 + lg * 4;  // multiple of 4
        const int bb = row0 >> 8;
        const int s0 = row0 & 255;
        if (which == 2) {
          unsigned long long pk = 0;
#pragma unroll
          for (int r = 0; r < 4; ++r)
            pk |= (unsigned long long)f2bf(acc[mf][nf][r] + bv) << (16 * r);
          *(unsigned long long*)&VTo[((size_t)(bb * 16 + hh) * 64 + dd) * 256 + s0] = pk;
        } else if (which == 0) {
          // Q pre-scaled by 1/sqrt(D)=0.125 (exact bf16 exponent shift)
#pragma unroll
          for (int r = 0; r < 4; ++r)
            Qo[((size_t)(bb * 16 + hh) * 256 + s0 + r) * 64 + dd] = f2bf((acc[mf][nf][r] + bv) * 0.125f);
        } else {
#pragma unroll
          for (int r = 0; r < 4; ++r)
            Ko[((size_t)(bb * 16 + hh) * 256 + s0 + r) * 64 + dd] = f2bf(acc[mf][nf][r] + bv);
        }
      }
    }
  } else {
#pragma unroll
    for (int nf = 0; nf < 4; ++nf) {
      const int col = bn0 + wc * 64 + nf * 16 + l15;
      const float bv = bias[col];
#pragma unroll
      for (int mf = 0; mf < 4; ++mf) {
#pragma unroll
        for (int r = 0; r < 4; ++r) {
          const int row = am0 + wr * 64 + mf * 16 + lg * 4 + r;
          const size_t idx = (size_t)row * 1024 + col;
          Out[idx] = Xres[idx] + acc[mf][nf][r] + bv;
        }
      }
    }
  }
}

// ---------------------------------------------------------------- fused attention (R14, FROZEN)
// 1 block per (b,h); 4 waves x 64 q rows; 8 key chunks of 32. K bulk-staged to
// LDS (granule-XOR swizzle, order-independent vmcnt(0)+sched_barrier handshake),
// T5 setprio on both MFMA clusters (+5us, m191), T13 defer-max, bias bf16,
// Q pre-scaled. 2 blocks/CU is this structure's optimum (R8/R13/R16 all worse).
__global__ __launch_bounds__(256, 2)
void attn_kernel(const unsigned short* __restrict__ Qg,
                 const unsigned short* __restrict__ Kg,
                 const unsigned short* __restrict__ VTg,
                 const unsigned short* __restrict__ biasbf,
                 unsigned short* __restrict__ ctx) {
  __shared__ unsigned short Ks[256 * 64];   // 32KB swizzled K
  __shared__ unsigned short P[4][64][40];   // per-wave [q][k32], pad 32->40 (20KB)
  const int lane = threadIdx.x & 63, wave = threadIdx.x >> 6;
  const int l15 = lane & 15, lg = lane >> 4;
  const int bh = blockIdx.x;
  const int bb = bh >> 4, hh = bh & 15;
  const size_t base = (size_t)bh * (256 * 64);
  const int q0 = wave * 64;

  // ---- bulk K stage: 2048 granules(16B); issue j covers rows (wave*8+j)*8..+7
#pragma unroll
  for (int j = 0; j < 8; ++j) {
    const int r0 = (wave * 8 + j) * 8;
    const int row = r0 + (lane >> 3);
    const int gsrc = (lane & 7) ^ (row & 7);
    g2l16(&Kg[base + (size_t)row * 64 + gsrc * 8], &Ks[r0 * 64]);
  }
  // Order-independent drain: ALL this wave's vmem done before signaling.
  asm volatile("s_waitcnt vmcnt(0)" ::: "memory");
  __builtin_amdgcn_sched_barrier(0);
  __builtin_amdgcn_s_barrier();                     // all waves' K staged

  // Q fragments (after barrier; pre-scaled by 0.125 in gemm0)
  bf16x8 qfr[4][2];
#pragma unroll
  for (int qi = 0; qi < 4; ++qi)
#pragma unroll
    for (int kc = 0; kc < 2; ++kc)
      qfr[qi][kc] = *(const bf16x8*)&Qg[base + (size_t)(q0 + qi * 16 + l15) * 64 + kc * 32 + lg * 8];

  f32x4 o[4][4] = {};
  float mrow[4], lrow[4];
#pragma unroll
  for (int i = 0; i < 4; ++i) { mrow[i] = -1e30f; lrow[i] = 0.f; }

#pragma unroll 1
  for (int c = 0; c < 8; ++c) {
    const int ck = c * 32;
    // V + bias issues first (global; longest latency to use)
    bf16x8 vb[4];
#pragma unroll
    for (int df = 0; df < 4; ++df)
      vb[df] = *(const bf16x8*)&VTg[base + (size_t)(df * 16 + l15) * 256 + ck + lg * 8];
    ushort4 bbf[2][4];
#pragma unroll
    for (int kr = 0; kr < 2; ++kr)
#pragma unroll
      for (int qi = 0; qi < 4; ++qi)
        bbf[kr][qi] = *(const ushort4*)&biasbf[(q0 + qi * 16 + l15) * 256 + ck + kr * 16 + lg * 4];
    // K fragments from LDS (swizzled granule)
    bf16x8 kf[2][2];
#pragma unroll
    for (int kr = 0; kr < 2; ++kr)
#pragma unroll
      for (int kc = 0; kc < 2; ++kc) {
        const int row = ck + kr * 16 + l15;
        const int g = (kc * 4 + lg) ^ (row & 7);
        kf[kr][kc] = *(const bf16x8*)&Ks[row * 64 + g * 8];
      }
    // S^T chunk [32k x 64q] = mfma(K, Q)  — T5: boost wave prio through MFMA cluster
    f32x4 s[2][4] = {};
    __builtin_amdgcn_s_setprio(1);
#pragma unroll
    for (int kr = 0; kr < 2; ++kr)
#pragma unroll
      for (int qi = 0; qi < 4; ++qi)
#pragma unroll
        for (int kc = 0; kc < 2; ++kc)
          s[kr][qi] = __builtin_amdgcn_mfma_f32_16x16x32_bf16(kf[kr][kc], qfr[qi][kc], s[kr][qi], 0, 0, 0);
    __builtin_amdgcn_s_setprio(0);

    // + bias (Q pre-scaled, so no multiply); per-q chunk max
    float cmax[4];
#pragma unroll
    for (int qi = 0; qi < 4; ++qi) cmax[qi] = -1e30f;
#pragma unroll
    for (int kr = 0; kr < 2; ++kr)
#pragma unroll
      for (int qi = 0; qi < 4; ++qi) {
        const unsigned short* bp = (const unsigned short*)&bbf[kr][qi];
#pragma unroll
        for (int r = 0; r < 4; ++r) {
          float v = s[kr][qi][r] + bf2f(bp[r]);
          s[kr][qi][r] = v;
          cmax[qi] = fmaxf(cmax[qi], v);
        }
      }
#pragma unroll
    for (int qi = 0; qi < 4; ++qi) {
      cmax[qi] = fmaxf(cmax[qi], __shfl_xor(cmax[qi], 16, 64));
      cmax[qi] = fmaxf(cmax[qi], __shfl_xor(cmax[qi], 32, 64));
    }
    // T13 defer-max: skip rescale when no q-row grew its max by >8
    int defer = 1;
#pragma unroll
    for (int qi = 0; qi < 4; ++qi) defer &= (cmax[qi] - mrow[qi] <= 8.f);
    const int full = !__all(defer);   // wave-uniform
    float resc[4];
#pragma unroll
    for (int qi = 0; qi < 4; ++qi) {
      if (full) {
        float mn = fmaxf(mrow[qi], cmax[qi]);
        resc[qi] = __expf(mrow[qi] - mn);
        mrow[qi] = mn;
      } else resc[qi] = 1.f;
    }
    float csum[4];
#pragma unroll
    for (int qi = 0; qi < 4; ++qi) csum[qi] = 0.f;
#pragma unroll
    for (int kr = 0; kr < 2; ++kr)
#pragma unroll
      for (int qi = 0; qi < 4; ++qi)
#pragma unroll
        for (int r = 0; r < 4; ++r) {
          float e = __expf(s[kr][qi][r] - mrow[qi]);
          s[kr][qi][r] = e;
          csum[qi] += e;
        }
#pragma unroll
    for (int qi = 0; qi < 4; ++qi) {
      csum[qi] += __shfl_xor(csum[qi], 16, 64);
      csum[qi] += __shfl_xor(csum[qi], 32, 64);
      lrow[qi] = lrow[qi] * resc[qi] + csum[qi];
    }
    // P -> LDS transposed to [q][k] (per-wave private), packed b64 writes
#pragma unroll
    for (int kr = 0; kr < 2; ++kr)
#pragma unroll
      for (int qi = 0; qi < 4; ++qi) {
        unsigned long long pk = 0;
#pragma unroll
        for (int r = 0; r < 4; ++r)
          pk |= (unsigned long long)f2bf(s[kr][qi][r]) << (16 * r);
        *(unsigned long long*)&P[wave][qi * 16 + l15][kr * 16 + lg * 4] = pk;
      }
    asm volatile("s_waitcnt lgkmcnt(0)" ::: "memory");
    // O rescale only on the full path
    if (full) {
#pragma unroll
      for (int qrf = 0; qrf < 4; ++qrf)
#pragma unroll
        for (int r = 0; r < 4; ++r) {
          float f = __shfl(resc[qrf], lg * 4 + r, 64);
#pragma unroll
          for (int df = 0; df < 4; ++df) o[qrf][df][r] *= f;
        }
    }
    // PV: A = P[q][k] from LDS, B = V chunk — T5 around the cluster
    bf16x8 pa[4];
#pragma unroll
    for (int qrf = 0; qrf < 4; ++qrf)
      pa[qrf] = *(const bf16x8*)&P[wave][qrf * 16 + l15][lg * 8];
    __builtin_amdgcn_s_setprio(1);
#pragma unroll
    for (int qrf = 0; qrf < 4; ++qrf)
#pragma unroll
      for (int df = 0; df < 4; ++df)
        o[qrf][df] = __builtin_amdgcn_mfma_f32_16x16x32_bf16(pa[qrf], vb[df], o[qrf][df], 0, 0, 0);
    __builtin_amdgcn_s_setprio(0);
  }

  // normalize and write ctx [B,S,E] bf16
#pragma unroll
  for (int qrf = 0; qrf < 4; ++qrf)
#pragma unroll
    for (int r = 0; r < 4; ++r) {
      float li = __shfl(lrow[qrf], lg * 4 + r, 64);
      float inv = 1.0f / li;
      const int q = q0 + qrf * 16 + lg * 4 + r;
#pragma unroll
      for (int df = 0; df < 4; ++df) {
        const int d = df * 16 + l15;
        ctx[((size_t)(bb * 256 + q) * 16 + hh) * 64 + d] = f2bf(o[qrf][df][r] * inv);
      }
    }
}

// ---------------------------------------------------------------- launch
extern "C" void kernel_launch(void* const* d_in, const int* in_sizes, int n_in,
                              void* d_out, int out_size, void* d_ws, size_t ws_size,
                              hipStream_t stream) {
  const float* x  = (const float*)d_in[0];
  const float* wi = (const float*)d_in[1];
  const float* bi = (const float*)d_in[2];
  const float* wo = (const float*)d_in[3];
  const float* bo = (const float*)d_in[4];
  const float* sb = (const float*)d_in[5];
  float* out = (float*)d_out;

  char* ws = (char*)d_ws;
  // ws layout (bytes): x_bf/ctx 33554432 | w_in 6291456 | w_out 2097152 | Q | K | VT
  unsigned short* xbf  = (unsigned short*)(ws);
  unsigned short* winb = (unsigned short*)(ws + 33554432u);
  unsigned short* wob  = (unsigned short*)(ws + 39845888u);
  unsigned short* Qb   = (unsigned short*)(ws + 41943040u);
  unsigned short* Kb   = (unsigned short*)(ws + 75497472u);
  unsigned short* VTb  = (unsigned short*)(ws + 109051904u);
  unsigned short* ctx  = xbf;   // x_bf dead after QKV GEMM; reuse for ctx
  unsigned short* sbbf = winb;  // w_in dead after gemm0; bias-bf16 cvt'd there

  cvt_kernel<<<16384, 256, 0, stream>>>(x, xbf, 16777216);
  cvt_kernel<<<3072, 256, 0, stream>>>(wi, winb, 3145728);
  cvt_kernel<<<1024, 256, 0, stream>>>(wo, wob, 1048576);

  // QKV: M=16384 N=3072 K=1024  (Q pre-scaled by 0.125 in epilogue)
  gemm_bt<0><<<dim3(128, 24), 256, 0, stream>>>(xbf, winb, bi, Qb, Kb, VTb, nullptr, nullptr);

  // bias -> bf16 into the now-dead w_in region (64 blocks, 65536 elems)
  cvt_kernel<<<64, 256, 0, stream>>>(sb, sbbf, 65536);

  // attention: one block per (b,h)
  attn_kernel<<<1024, 256, 0, stream>>>(Qb, Kb, VTb, sbbf, ctx);

  // out-proj + residual: M=16384 N=1024 K=1024
  gemm_bt<1><<<dim3(128, 8), 256, 0, stream>>>(ctx, wob, bo, nullptr, nullptr, nullptr, x, out);
}